// Round 16
// baseline (32.925 us; speedup 1.0000x reference)
//
#include <hip/hip_runtime.h>

namespace {
constexpr int kM = 4, kJ = 2, kI = 3, kL = 2, kW = 9;
constexpr float kInvLn2 = 1.4426950408889634f;

__device__ __forceinline__ float fexp2(float x) { return __builtin_amdgcn_exp2f(x); }

// Single fused kernel, ALL-SCALAR body (no vector types anywhere in the hot
// path — R12 calibration showed ~1100cy/wave of v2f pack/unpack churn).
//
// sdp: 4 records of 20 floats (80B, 16B-aligned) + nothing else. Record m:
//   [ 0] An0   [ 1] An1   [ 2] B0n0  [ 3] B0n1
//   [ 4] B1n0  [ 5] B1n1  [ 6] w0n0  [ 7] w0n1
//   [ 8] w1n0  [ 9] w1n1  [10] C000  [11] C001
//   [12] C010  [13] C011  [14] C100  [15] C101
//   [16] C110  [17] C111  [18] D0    [19] D1
// (suffix j: premise; C{l}{lp}; all A/B/w negated+log2-scaled so
//  msN_j = An_j + sx*(B0n_j + w0n_j*sx) + sy*(B1n_j + w1n_j*sy) = -ms/ln2 <= 0)
__global__ __launch_bounds__(256) void algelogic_one(
    const float* __restrict__ state,
    const float* __restrict__ constants,
    const float* __restrict__ gammas,
    const float* __restrict__ W_body,
    const float* __restrict__ b_body,
    const float* __restrict__ W_head,
    const float* __restrict__ b_head,
    float* __restrict__ out) {
  __shared__ float sdp[80];
  const int t = threadIdx.x;
  const int b = blockIdx.x * 256 + t;

  // ---- state loads first (in flight during the fold) ----
  const float2* sr = reinterpret_cast<const float2*>(state) + (size_t)b * kW;
  float s0[kW], s1[kW];
#pragma unroll
  for (int w = 0; w < kW; ++w) {
    const float2 v = sr[w];
    s0[w] = v.x; s1[w] = v.y;
  }

  // ---- param fold: wave0 lanes 0-7 coeffs+C; wave1 lanes 0-3 D ----
  if (t < 8) {
    const int mj = t, m = t >> 1, j = t & 1;
    const float g0 = fminf(fmaxf(gammas[mj * kL + 0], 0.f), 1.f);
    const float g1 = fminf(fmaxf(gammas[mj * kL + 1], 0.f), 1.f);
    const float w0 = 1.f - g0, w1 = 1.f - g1;
    const float c0 = constants[mj * kL + 0], c1 = constants[mj * kL + 1];
    const float gavg = 0.5f * (g0 + g1);
    float* base = sdp + m * 20;
    base[0 + j] = -(w0 * c0 * c0 + w1 * c1 * c1) * kInvLn2;  // An
    base[2 + j] = 2.f * w0 * c0 * kInvLn2;                   // B0n
    base[4 + j] = 2.f * w1 * c1 * kInvLn2;                   // B1n
    base[6 + j] = -w0 * kInvLn2;                             // w0n
    base[8 + j] = -w1 * kInvLn2;                             // w1n
#pragma unroll
    for (int l = 0; l < kL; ++l)
#pragma unroll
      for (int lp = 0; lp < kL; ++lp) {
        float acc = 0.f;
#pragma unroll
        for (int i = 0; i < kI; ++i)
          acc += W_head[(m * kL + l) * kI + i] * W_body[(mj * kI + i) * kL + lp];
        base[10 + (l * 2 + lp) * 2 + j] = gavg * acc;        // C[l][lp], j
      }
  } else if (t >= 64 && t < 68) {
    const int m = t - 64;
#pragma unroll
    for (int l = 0; l < kL; ++l) {
      float d = b_head[m * kL + l];
#pragma unroll
      for (int j = 0; j < kJ; ++j) {
        const int mj = m * kJ + j;
        const float g0 = fminf(fmaxf(gammas[mj * kL + 0], 0.f), 1.f);
        const float g1 = fminf(fmaxf(gammas[mj * kL + 1], 0.f), 1.f);
        const float gavg = 0.5f * (g0 + g1);
        float acc = 0.f;
#pragma unroll
        for (int i = 0; i < kI; ++i)
          acc += W_head[(m * kL + l) * kI + i] * b_body[mj * kI + i];
        d += gavg * acc;
      }
      sdp[m * 20 + 18 + l] = d;
    }
  }
  __syncthreads();

  float Cs = 0.f, X0 = 0.f, X1 = 0.f, K = 0.f;

#pragma unroll 1   // one m live at a time: ~60 VGPR, no spill
  for (int m = 0; m < kM; ++m) {
    const float4* P4 = reinterpret_cast<const float4*>(sdp + m * 20);
    const float4 f0 = P4[0], f1 = P4[1], f2 = P4[2], f3 = P4[3], f4 = P4[4];
    // f0: An0 An1 B0n0 B0n1 | f1: B1n0 B1n1 w0n0 w0n1 | f2: w1n0 w1n1 C000 C001
    // f3: C010 C011 C100 C101 | f4: C110 C111 D0 D1

    float p0 = 1e-35f, p1 = 1e-35f;        // psum (guard: rcp never sees 0)
    float a0 = 0.f, a1 = 0.f;              // pb0 (e*sx)
    float b0 = 0.f, b1 = 0.f;              // pb1 (e*sy)
    float g0 = 0.f, g1 = 0.f;              // pmq (e*msN)
#pragma unroll
    for (int w = 0; w < kW; ++w) {
      const float sx = s0[w], sy = s1[w];
      // premise j0
      float u = fmaf(f1.z, sx, f0.z);      // w0n0*sx + B0n0
      float mN0 = fmaf(u, sx, f0.x);       // + An0
      float v = fmaf(f2.x, sy, f1.x);      // w1n0*sy + B1n0
      mN0 = fmaf(v, sy, mN0);              // msN_j0 (<= 0, log2 units)
      const float e0 = fexp2(mN0);
      p0 += e0;
      a0 = fmaf(e0, sx, a0);
      b0 = fmaf(e0, sy, b0);
      g0 = fmaf(e0, mN0, g0);
      // premise j1
      float u1 = fmaf(f1.w, sx, f0.w);     // w0n1*sx + B0n1
      float mN1 = fmaf(u1, sx, f0.y);      // + An1
      float v1 = fmaf(f2.y, sy, f1.y);     // w1n1*sy + B1n1
      mN1 = fmaf(v1, sy, mN1);
      const float e1 = fexp2(mN1);
      p1 += e1;
      a1 = fmaf(e1, sx, a1);
      b1 = fmaf(e1, sy, b1);
      g1 = fmaf(e1, mN1, g1);
    }

    const float i0 = __builtin_amdgcn_rcpf(p0);
    const float i1 = __builtin_amdgcn_rcpf(p1);
    const float bb00 = a0 * i0, bb10 = b0 * i0;   // best_j0: l=0, l=1
    const float bb01 = a1 * i1, bb11 = b1 * i1;   // best_j1
    const float mq2 = fmaf(g0, i0, g1 * i1);      // -mq/ln2 (sum over j)
    const float conf = fexp2(mq2);                // exp(-mq)

    // r_l = D_l + sum_j (C[l][0]_j*bb0_j + C[l][1]_j*bb1_j)
    float r0 = fmaf(f2.z, bb00, f4.z);
    r0 = fmaf(f3.x, bb10, r0);
    r0 = fmaf(f2.w, bb01, r0);
    r0 = fmaf(f3.y, bb11, r0);
    float r1 = fmaf(f3.z, bb00, f4.w);
    r1 = fmaf(f4.x, bb10, r1);
    r1 = fmaf(f3.w, bb01, r1);
    r1 = fmaf(f4.y, bb11, r1);

    Cs += conf;
    X0 = fmaf(conf, r0, X0);
    X1 = fmaf(conf, r1, X1);
    K = fmaf(conf, fmaf(r0, r0, r1 * r1), K);
  }

  const float X02 = 2.f * X0, X12 = 2.f * X1;
  float* orow = out + (size_t)b * kW;
#pragma unroll
  for (int w = 0; w < kW; ++w) {
    const float sx = s0[w], sy = s1[w];
    const float qs = fmaf(sx, sx, sy * sy);
    // out = 2X0*sx + 2X1*sy - Cs*(sx^2+sy^2) - K
    orow[w] = fmaf(X02, sx, fmaf(X12, sy, fmaf(-Cs, qs, -K)));
  }
}
}  // namespace

extern "C" void kernel_launch(void* const* d_in, const int* in_sizes, int n_in,
                              void* d_out, int out_size, void* d_ws, size_t ws_size,
                              hipStream_t stream) {
  const float* state     = (const float*)d_in[0];
  const float* constants = (const float*)d_in[1];
  const float* gammas    = (const float*)d_in[2];
  const float* W_body    = (const float*)d_in[3];
  const float* b_body    = (const float*)d_in[4];
  const float* W_head    = (const float*)d_in[5];
  const float* b_head    = (const float*)d_in[6];
  float* out = (float*)d_out;

  const int B = in_sizes[0] / (kW * kL);   // 1048576
  hipLaunchKernelGGL(algelogic_one, dim3(B / 256), dim3(256), 0, stream,
                     state, constants, gammas, W_body, b_body, W_head, b_head, out);
}